// Round 12
// baseline (127.199 us; speedup 1.0000x reference)
//
#include <hip/hip_runtime.h>
#include <stdint.h>

typedef unsigned long long u64;
typedef unsigned int u32;

#define NB    4000            // boxes
#define NCLS  80              // foreground classes
#define MAXI  100             // max instances
#define NKEY  (NCLS * MAXI)   // 8000 candidate keys
#define SMAX  4096
#define SELT  448             // per-class selection target
#define NTH   512             // k_nms block size

__device__ __forceinline__ u32 mono_f32(float f) {
    u32 u = __float_as_uint(f);
    return (u & 0x80000000u) ? ~u : (u | 0x80000000u);
}

// wave helper: descending scan of 1024-bin hist; find bin B where suffix count
// reaches T; A = #keys in bins > B. Requires hist total >= T >= 1.
__device__ __forceinline__ void find_cross(const u32* hist, int T, int lane,
                                           int* outB, int* outA) {
    int running = 0, B = -1, A = 0;
    for (int g = 0; g < 16 && B < 0; ++g) {
        const int d = 1023 - (g * 64 + lane);     // lane 0 = highest bin
        const int cnt = (int)hist[d];
        int pre = cnt;
        #pragma unroll
        for (int off = 1; off < 64; off <<= 1) {
            const int v = __shfl_up(pre, off);
            if (lane >= off) pre += v;
        }
        const int incl = running + pre;
        const int excl = incl - cnt;
        const u64 hm = __ballot(excl < T && incl >= T);
        if (hm != 0ull) {
            const int hl = (int)__builtin_ctzll(hm);
            B = __shfl(d, hl);
            A = __shfl(excl, hl);
        }
        running = __shfl(incl, 63);
    }
    *outB = B; *outA = A;
}

// ---------------- K1: fully fused per-class NMS ----------------------------
// gather scores -> radix-select top-M -> bitonic sort -> greedy walk with
// inline IoU vs register-resident kept boxes. No suppression bitmap.
__global__ __launch_bounds__(NTH) void k_nms(const float4* __restrict__ boxes,
                                             const float* __restrict__ scores,
                                             const float* __restrict__ conf_t,
                                             const float* __restrict__ nms_t,
                                             u64* __restrict__ cand) {
    __shared__ u64 skey[SMAX];                 // 32 KB
    __shared__ float4 sboxes[NB];              // 64 KB
    __shared__ u32 hist[1024];                 // 4 KB
    __shared__ int wsum[8];
    __shared__ int sh_kept, sh_M, sh_B, sh_A, sh_B2, sh_nvalid;

    const int c    = blockIdx.x;
    const int tid  = threadIdx.x;
    const int lane = tid & 63;
    const int wid  = tid >> 6;
    const float conf = *conf_t;
    const float t    = *nms_t;

    // stage all boxes to LDS (consumed by the walk, many barriers later)
    for (int i = tid; i < NB; i += NTH) sboxes[i] = boxes[i];

    // gather this class's scores, build keys in regs
    u64 own[8];
    int cnt = 0;
    #pragma unroll
    for (int q = 0; q < 8; ++q) {
        const int b = tid + q * NTH;
        u64 k = 0;
        if (b < NB) {
            const float s = scores[b * 81 + c + 1];
            if (s > conf)
                k = ((u64)mono_f32(s) << 32) | (u64)(0xFFFFFFFFu - (u32)b);
        }
        own[q] = k;
        cnt += (k != 0ull);
    }
    #pragma unroll
    for (int off = 1; off < 64; off <<= 1) cnt += __shfl_xor(cnt, off);
    if (lane == 0) wsum[wid] = cnt;
    __syncthreads();
    if (tid == 0) {
        int tt = 0;
        #pragma unroll
        for (int w = 0; w < 8; ++w) tt += wsum[w];
        sh_nvalid = tt;
    }
    __syncthreads();
    const int nvalid = sh_nvalid;

    bool full = (nvalid <= 512);
    int kept = 0;

    for (int attempt = 0; attempt < 2; ++attempt) {
        int M;
        if (!full) {
            // ---- level-1 histogram on key bits [63:54] ----
            for (int i = tid; i < 1024; i += NTH) hist[i] = 0;
            if (tid == 0) sh_M = 0;
            __syncthreads();
            #pragma unroll
            for (int q = 0; q < 8; ++q)
                if (own[q] != 0ull)
                    atomicAdd(&hist[(u32)(own[q] >> 54) & 1023u], 1u);
            __syncthreads();
            if (tid < 64) {
                int B, A;
                find_cross(hist, SELT, lane, &B, &A);
                if (lane == 0) { sh_B = B; sh_A = A; }
            }
            __syncthreads();
            const int B = sh_B, A = sh_A;
            // ---- level-2 histogram on bits [53:44], keys in bin B ----
            for (int i = tid; i < 1024; i += NTH) hist[i] = 0;
            __syncthreads();
            #pragma unroll
            for (int q = 0; q < 8; ++q)
                if (own[q] != 0ull && ((u32)(own[q] >> 54) & 1023u) == (u32)B)
                    atomicAdd(&hist[(u32)(own[q] >> 44) & 1023u], 1u);
            __syncthreads();
            if (tid < 64) {
                int B2, A2;
                find_cross(hist, SELT - A, lane, &B2, &A2);
                if (lane == 0) sh_B2 = B2;
            }
            __syncthreads();
            const int B2 = sh_B2;
            // ---- compact selected keys into skey[0..M) ----
            #pragma unroll
            for (int q = 0; q < 8; ++q) {
                bool sel = false;
                if (own[q] != 0ull) {
                    const int d = (int)((u32)(own[q] >> 54) & 1023u);
                    sel = (d > B) ||
                          (d == B && (int)((u32)(own[q] >> 44) & 1023u) >= B2);
                }
                const u64 bm = __ballot(sel);
                int wbase = 0;
                if (lane == 0 && bm) wbase = atomicAdd(&sh_M, (int)__popcll(bm));
                wbase = __shfl(wbase, 0);
                if (sel)
                    skey[wbase + (int)__popcll(bm & ((1ull << lane) - 1ull))] = own[q];
            }
            __syncthreads();
            M = sh_M;
        } else {
            if (tid == 0) sh_M = 0;
            __syncthreads();
            #pragma unroll
            for (int q = 0; q < 8; ++q) {
                const bool sel = (own[q] != 0ull);
                const u64 bm = __ballot(sel);
                int wbase = 0;
                if (lane == 0 && bm) wbase = atomicAdd(&sh_M, (int)__popcll(bm));
                wbase = __shfl(wbase, 0);
                if (sel)
                    skey[wbase + (int)__popcll(bm & ((1ull << lane) - 1ull))] = own[q];
            }
            __syncthreads();
            M = sh_M;                          // == nvalid
        }

        int S = 64;
        while (S < M) S <<= 1;
        for (int i = M + tid; i < S; i += NTH) skey[i] = 0;
        __syncthreads();

        // ---- bitonic sort descending: j>=64 in LDS, j<=32 via shfl ----
        for (int k2 = 2; k2 <= S; k2 <<= 1) {
            for (int j = k2 >> 1; j >= 64; j >>= 1) {
                for (int p = tid; p < (S >> 1); p += NTH) {
                    const int i0 = ((p & ~(j - 1)) << 1) | (p & (j - 1));
                    const u64 a = skey[i0], b = skey[i0 | j];
                    const bool up = ((i0 & k2) == 0);
                    if (up ? (a < b) : (a > b)) { skey[i0] = b; skey[i0 | j] = a; }
                }
                __syncthreads();
            }
            for (int base = 0; base < S; base += NTH) {
                const int i = base + tid;
                if (i < S) {
                    u64 x = skey[i];
                    #pragma unroll
                    for (int j2 = 32; j2 >= 1; j2 >>= 1) {
                        if (j2 < k2) {
                            const u64 y = __shfl_xor(x, j2);
                            const bool wantmax = (((i & k2) == 0) == ((i & j2) == 0));
                            x = wantmax ? (x > y ? x : y) : (x < y ? x : y);
                        }
                    }
                    skey[i] = x;
                }
            }
            __syncthreads();
        }

        // ---- serial greedy walk, wave 0; inline IoU vs kept-in-registers --
        // lane l owns kept slots l (kb0) and 64+l (kb1). 2-deep LDS pipeline.
        if (tid < 64) {
            float4 kb0 = make_float4(0.f,0.f,0.f,0.f), kb1 = kb0;
            float ka0 = 0.f, ka1 = 0.f;
            int kp = 0;
            if (M > 0) {
                u64 kcur = skey[0];
                float4 cbn = sboxes[0xFFFFFFFFu - (u32)kcur];
                u64 knext = (M > 1) ? skey[1] : 0ull;
                for (int p = 0; p < M && kp < MAXI; ++p) {
                    const u64 kk = kcur;
                    const float4 cb = cbn;
                    // advance pipeline: box for p+1, key for p+2
                    if (p + 1 < M) cbn = sboxes[0xFFFFFFFFu - (u32)knext];
                    kcur = knext;
                    if (p + 2 < M) knext = skey[p + 2];
                    const float ca = (cb.z - cb.x) * (cb.w - cb.y);
                    bool sup;
                    {
                        const float ix1 = fmaxf(cb.x, kb0.x), iy1 = fmaxf(cb.y, kb0.y);
                        const float ix2 = fminf(cb.z, kb0.z), iy2 = fminf(cb.w, kb0.w);
                        const float inter = fmaxf(ix2 - ix1, 0.f) * fmaxf(iy2 - iy1, 0.f);
                        sup = (lane < kp) && (inter / (ka0 + ca - inter + 1e-9f) > t);
                    }
                    {
                        const float ix1 = fmaxf(cb.x, kb1.x), iy1 = fmaxf(cb.y, kb1.y);
                        const float ix2 = fminf(cb.z, kb1.z), iy2 = fminf(cb.w, kb1.w);
                        const float inter = fmaxf(ix2 - ix1, 0.f) * fmaxf(iy2 - iy1, 0.f);
                        sup |= (64 + lane < kp) && (inter / (ka1 + ca - inter + 1e-9f) > t);
                    }
                    if (__ballot(sup) == 0ull) {
                        if (lane == (kp & 63)) {
                            if (kp < 64) { kb0 = cb; ka0 = ca; }
                            else         { kb1 = cb; ka1 = ca; }
                        }
                        if (lane == 0) {
                            const u32 b = 0xFFFFFFFFu - (u32)kk;
                            const u32 flat = (u32)(c * NB + (int)b);
                            cand[c * MAXI + kp] =
                                (kk & 0xFFFFFFFF00000000ull) | (u64)(0xFFFFFFFFu - flat);
                        }
                        kp++;
                    }
                }
            }
            if (lane == 0) sh_kept = kp;
        }
        __syncthreads();
        kept = sh_kept;

        if (kept >= MAXI || full) break;   // exact: walked true top-M prefix
        full = true;                       // rare fallback: full sort + re-walk
    }

    for (int s = tid; s < MAXI; s += NTH)
        if (s >= kept) cand[c * MAXI + s] = 0;
}

// ---------------- K2: global top-100 via iterative radix-select + emit -----
__global__ __launch_bounds__(1024) void k_final(const u64* __restrict__ cand,
                                                const float4* __restrict__ boxes,
                                                float* __restrict__ out) {
    __shared__ u32 hist[1024];
    __shared__ u64 sel[256];
    __shared__ int wsum[16];
    __shared__ int sh_total, sh_A, sh_B, sh_bits, sh_M, sh_cnt;
    __shared__ u64 sh_prefix;

    const int tid  = threadIdx.x;
    const int lane = tid & 63;
    const int wid  = tid >> 6;

    u64 myk[8];
    int cnt = 0;
    #pragma unroll
    for (int q = 0; q < 8; ++q) {
        const int i = tid + (q << 10);
        myk[q] = (i < NKEY) ? cand[i] : 0ull;
        cnt += (myk[q] != 0ull);
    }
    #pragma unroll
    for (int off = 1; off < 64; off <<= 1) cnt += __shfl_xor(cnt, off);
    if (lane == 0) wsum[wid] = cnt;
    if (tid < 256) sel[tid] = 0;
    __syncthreads();
    if (tid == 0) {
        int t = 0;
        #pragma unroll
        for (int w = 0; w < 16; ++w) t += wsum[w];
        sh_total = t; sh_A = 0; sh_bits = 0; sh_prefix = 0; sh_cnt = 0;
    }
    __syncthreads();
    const int total = sh_total;
    const int Tt = (total < MAXI) ? total : MAXI;

    if (total > 0) {
        // iterative 10-bit radix-select until selected count M <= 256
        for (int lvl = 0; lvl < 6; ++lvl) {
            hist[tid & 1023] = 0;
            __syncthreads();
            const int bits = sh_bits;
            const u64 pref = sh_prefix;
            const int shift = 54 - bits;
            #pragma unroll
            for (int q = 0; q < 8; ++q) {
                const u64 k = myk[q];
                if (k != 0ull && (bits == 0 || (k >> (64 - bits)) == pref))
                    atomicAdd(&hist[(u32)(k >> shift) & 1023u], 1u);
            }
            __syncthreads();
            if (tid < 64) {
                const int T = Tt - sh_A;
                int B, A;
                find_cross(hist, T, lane, &B, &A);
                if (lane == 0) { sh_B = B; sh_A += A; }
            }
            __syncthreads();
            if (tid == 0) {
                sh_M = sh_A + (int)hist[sh_B];
                sh_prefix = (sh_prefix << 10) | (u32)sh_B;
                sh_bits += 10;
            }
            __syncthreads();
            if (sh_M <= 256) break;
        }
        // compact selected (prefix >= sh_prefix) into sel[0..M)
        const int bits = sh_bits;
        const u64 pref = sh_prefix;
        #pragma unroll
        for (int q = 0; q < 8; ++q) {
            const u64 k = myk[q];
            const bool s = (k != 0ull) && ((k >> (64 - bits)) >= pref);
            const u64 bm = __ballot(s);
            int wbase = 0;
            if (lane == 0 && bm) wbase = atomicAdd(&sh_cnt, (int)__popcll(bm));
            wbase = __shfl(wbase, 0);
            if (s) sel[wbase + (int)__popcll(bm & ((1ull << lane) - 1ull))] = k;
        }
    }

    // defaults first, then rank-by-count scatter (unique keys -> unique ranks)
    if (tid < MAXI) {
        out[tid*5+0] = 0.0f; out[tid*5+1] = 0.0f; out[tid*5+2] = 0.0f;
        out[tid*5+3] = 0.0f; out[tid*5+4] = 0.0f;
        out[500 + tid] = -1.0f;
    }
    __syncthreads();
    if (tid < 256) {
        const u64 my = sel[tid];
        if (my != 0ull) {
            int r = 0;
            for (int j = 0; j < 256; ++j) r += (sel[j] > my);
            if (r < MAXI) {
                const u32 mono = (u32)(my >> 32);
                const float sc = __uint_as_float(mono ^ 0x80000000u);
                const u32 flat = 0xFFFFFFFFu - (u32)my;
                const int b    = (int)(flat % NB);
                const float4 bb = boxes[b];
                out[r*5+0] = bb.x; out[r*5+1] = bb.y;
                out[r*5+2] = bb.z; out[r*5+3] = bb.w;
                out[r*5+4] = sc;
                out[500 + r] = (float)(flat / NB);
            }
        }
    }
}

extern "C" void kernel_launch(void* const* d_in, const int* in_sizes, int n_in,
                              void* d_out, int out_size, void* d_ws, size_t ws_size,
                              hipStream_t stream) {
    const float4* bboxes = (const float4*)d_in[0];
    const float*  scores = (const float*)d_in[1];
    const float*  conf_t = (const float*)d_in[2];
    const float*  nms_t  = (const float*)d_in[3];

    u64* cand = (u64*)d_ws;                      // 64,000 B

    k_nms<<<NCLS, NTH, 0, stream>>>(bboxes, scores, conf_t, nms_t, cand);
    k_final<<<1, 1024, 0, stream>>>(cand, bboxes, (float*)d_out);
}